// Round 3
// baseline (818.681 us; speedup 1.0000x reference)
//
#include <hip/hip_runtime.h>
#include <cstddef>
#include <cstdint>

// Problem constants (from setup_inputs)
#define AA 512      // atoms
#define KK 256      // atom size
#define TT 16384    // signal length
#define BB 4        // batch
#define PP 128      // pad = K/2
#define LL 16385    // feature map length = T + 2P - K + 1
#define LPAD 16388  // fm row stride, padded to multiple of 4 for float4 stores
#define NC 65       // number of 256-wide chunks covering LL

static __device__ __forceinline__ int swz(int i){ return i + (i >> 5); }  // LDS bank swizzle

// ---------------- normalize dictionary atoms ----------------
__global__ void k_norm(const float* __restrict__ d, float* __restrict__ dn){
  int a = blockIdx.x, t = threadIdx.x;
  float v = d[a*KK + t];
  float s = v*v;
  #pragma unroll
  for (int off = 32; off > 0; off >>= 1) s += __shfl_down(s, off, 64);
  __shared__ float red[4];
  if ((t & 63) == 0) red[t >> 6] = s;
  __syncthreads();
  float tot = red[0] + red[1] + red[2] + red[3];
  dn[a*KK + t] = v / (sqrtf(tot) + 1e-8f);
}

// ---------------- zero output ----------------
__global__ void k_zero(float* __restrict__ out){
  int i = blockIdx.x*blockDim.x + threadIdx.x;
  if (i < BB*TT) out[i] = 0.f;
}

// ---------------- 16-position ring-buffer correlation core ----------------
// acc[j] = sum_k dnrow[k] * s_r[swz(16*tx + j + k)]   for j = 0..15, k = 0..255
__device__ __forceinline__ void corr16(const float* __restrict__ s_r,
                                       const float* __restrict__ dnrow,
                                       int tx, float acc[16]){
  const int base = tx*16;
  float r[16];
  #pragma unroll
  for (int j = 0; j < 16; ++j){ int i = base + j; r[j] = s_r[swz(i)]; }
  #pragma unroll
  for (int j = 0; j < 16; ++j) acc[j] = 0.f;
  for (int kb = 0; kb < 16; ++kb){
    #pragma unroll
    for (int kk = 0; kk < 16; ++kk){
      const int k = kb*16 + kk;
      const float w = dnrow[k];
      #pragma unroll
      for (int j = 0; j < 16; ++j)
        acc[j] = fmaf(w, r[(kk + j) & 15], acc[j]);
      const int i = base + k + 16;       // next needed value (<= 511)
      r[kk] = s_r[swz(i)];
    }
  }
}

// ---------------- initial feature map + chunk maxima ----------------
// block: 256 thr = 16 tx (positions) x 16 ty (atoms); tile = 16 atoms x 256 positions
__global__ __launch_bounds__(256) void k_fm_init(const float* __restrict__ x,
                                                 const float* __restrict__ dn,
                                                 float* __restrict__ fm,
                                                 float* __restrict__ cmv,
                                                 int* __restrict__ cml){
  const int lt = blockIdx.x, at = blockIdx.y, b = blockIdx.z;
  const int l0 = lt*256, a0 = at*16;
  const int tid = threadIdx.x;
  const int tx = tid & 15, ty = tid >> 4;

  __shared__ float s_r[528];          // 512 swizzled floats
  __shared__ float s_dn[16*257];      // 16 atoms, padded stride

  for (int i = tid; i < 512; i += 256){
    int m = l0 + i;                   // padded-coordinate index
    int t = m - PP;
    float v = (t >= 0 && t < TT) ? x[b*TT + t] : 0.f;
    s_r[swz(i)] = v;
  }
  for (int i = tid; i < 16*KK; i += 256){
    int aa = i >> 8, k = i & 255;
    s_dn[aa*257 + k] = dn[(size_t)(a0 + aa)*KK + k];
  }
  __syncthreads();

  float acc[16];
  corr16(s_r, &s_dn[ty*257], tx, acc);

  const int base = tx*16;
  const size_t rowoff = ((size_t)b*AA + a0 + ty)*LPAD + l0 + base;
  float best; int bestl;
  if (l0 + 256 <= LL){
    #pragma unroll
    for (int q = 0; q < 4; ++q){
      float4 v4; v4.x = acc[4*q]; v4.y = acc[4*q+1]; v4.z = acc[4*q+2]; v4.w = acc[4*q+3];
      *(float4*)(fm + rowoff + 4*q) = v4;
    }
    best = acc[0]; int bj = 0;
    #pragma unroll
    for (int j = 1; j < 16; ++j) if (acc[j] > best){ best = acc[j]; bj = j; }
    bestl = l0 + base + bj;
  } else {
    best = -1e30f; bestl = 0;
    #pragma unroll
    for (int j = 0; j < 16; ++j){
      int l = l0 + base + j;
      if (l < LL){
        fm[rowoff + j] = acc[j];
        if (acc[j] > best){ best = acc[j]; bestl = l; }
      }
    }
  }
  // reduce across the 16 tx lanes (same ty within the wave)
  #pragma unroll
  for (int m = 1; m < 16; m <<= 1){
    float ov = __shfl_xor(best, m, 64);
    int   ol = __shfl_xor(bestl, m, 64);
    if (ov > best || (ov == best && ol < bestl)){ best = ov; bestl = ol; }
  }
  if (tx == 0){
    size_t ci = ((size_t)b*AA + a0 + ty)*NC + lt;
    cmv[ci] = best; cml[ci] = bestl;
  }
}

// ---------------- global argmax over chunk maxima ----------------
__global__ void k_argmax(const float* __restrict__ cmv, const int* __restrict__ cml,
                         float* __restrict__ selv, int* __restrict__ sela, int* __restrict__ selp,
                         const int* __restrict__ nit, int it){
  if (it >= *nit) return;
  int b = blockIdx.x, tid = threadIdx.x;
  const float* v  = cmv + (size_t)b*AA*NC;
  const int*   pl = cml + (size_t)b*AA*NC;
  float best = -1e30f; int ba = 0, bl = 0;
  for (int i = tid; i < AA*NC; i += 256){
    float vv = v[i];
    if (vv > best){ best = vv; ba = i/NC; bl = pl[i]; }  // ascending i = flat tie order
  }
  __shared__ float sv[256]; __shared__ int sa[256]; __shared__ int sl[256];
  sv[tid] = best; sa[tid] = ba; sl[tid] = bl;
  __syncthreads();
  for (int s = 128; s > 0; s >>= 1){
    if (tid < s){
      float ov = sv[tid+s]; int oa = sa[tid+s], ol = sl[tid+s];
      bool take = ov > sv[tid] ||
                  (ov == sv[tid] && (oa < sa[tid] || (oa == sa[tid] && ol < sl[tid])));
      if (take){ sv[tid] = ov; sa[tid] = oa; sl[tid] = ol; }
    }
    __syncthreads();
  }
  if (tid == 0){ selv[b] = sv[0]; sela[b] = sa[0]; selp[b] = sl[0]; }
}

// ---------------- add selected atom into output reconstruction ----------------
__global__ void k_rec(const float* __restrict__ dn, const float* __restrict__ selv,
                      const int* __restrict__ sela, const int* __restrict__ selp,
                      float* __restrict__ out, const int* __restrict__ nit, int it){
  if (it >= *nit) return;
  int b = blockIdx.x, i = threadIdx.x;
  float val = selv[b]; int c = sela[b], pos = selp[b];
  int t = pos + i - PP;
  if (t >= 0 && t < TT) out[b*TT + t] += val * dn[c*KK + i];
}

// ---------------- incremental fm update: fm[b][a][pos+s] -= val * G(a,c,s) ----------------
// block: 16 atoms x 256 s-values; s = s0 + 16*tx + j - 256, s0 in {0, 256}
__global__ __launch_bounds__(256) void k_fmupd(const float* __restrict__ dn,
                                               const float* __restrict__ selv,
                                               const int* __restrict__ sela,
                                               const int* __restrict__ selp,
                                               float* __restrict__ fm,
                                               const int* __restrict__ nit, int it){
  if (it >= *nit) return;
  const int s0 = blockIdx.x*256, a0 = blockIdx.y*16, b = blockIdx.z;
  const float val = selv[b]; const int c = sela[b], pos = selp[b];
  const int tid = threadIdx.x, tx = tid & 15, ty = tid >> 4;

  __shared__ float s_e[528];          // zero-extended dn[c], window [s0, s0+512)
  __shared__ float s_dn[16*257];

  for (int i = tid; i < 512; i += 256){
    int k = s0 + i - 256;             // e[idx] = dn_c[idx-256], 0 outside [0,K)
    float v = (k >= 0 && k < KK) ? dn[(size_t)c*KK + k] : 0.f;
    s_e[swz(i)] = v;
  }
  for (int i = tid; i < 16*KK; i += 256){
    int aa = i >> 8, k = i & 255;
    s_dn[aa*257 + k] = dn[(size_t)(a0 + aa)*KK + k];
  }
  __syncthreads();

  float acc[16];                       // acc[j] = G(a0+ty, c, s0 + 16*tx + j - 256)
  corr16(s_e, &s_dn[ty*257], tx, acc);

  const size_t rb = ((size_t)b*AA + a0 + ty)*LPAD;
  const int lb = pos - 256 + s0 + tx*16;
  #pragma unroll
  for (int j = 0; j < 16; ++j){
    int l = lb + j;
    if (l >= 0 && l < LL) fm[rb + l] -= val * acc[j];
  }
}

// ---------------- refresh chunk maxima over touched chunks ----------------
__global__ void k_cmref(const float* __restrict__ fm, float* __restrict__ cmv,
                        int* __restrict__ cml, const int* __restrict__ selp,
                        const int* __restrict__ nit, int it){
  if (it >= *nit) return;
  int b = blockIdx.z, a0 = blockIdx.y*16;
  int pos = selp[b];
  int lo = pos - 255; if (lo < 0) lo = 0;
  int hi = pos + 255; if (hi > LL-1) hi = LL-1;
  int ch = (lo >> 8) + blockIdx.x;
  if (ch > (hi >> 8)) return;
  int tx = threadIdx.x & 15, ty = threadIdx.x >> 4;
  const size_t rb = ((size_t)b*AA + a0 + ty)*LPAD;
  int lbase = ch*256 + tx*16;
  float best = -1e30f; int bestl = 0;
  #pragma unroll
  for (int j = 0; j < 16; ++j){
    int l = lbase + j;
    if (l < LL){
      float v = fm[rb + l];
      if (v > best){ best = v; bestl = l; }
    }
  }
  #pragma unroll
  for (int m = 1; m < 16; m <<= 1){
    float ov = __shfl_xor(best, m, 64);
    int   ol = __shfl_xor(bestl, m, 64);
    if (ov > best || (ov == best && ol < bestl)){ best = ov; bestl = ol; }
  }
  if (tx == 0){
    size_t ci = ((size_t)b*AA + a0 + ty)*NC + ch;
    cmv[ci] = best; cml[ci] = bestl;
  }
}

extern "C" void kernel_launch(void* const* d_in, const int* in_sizes, int n_in,
                              void* d_out, int out_size, void* d_ws, size_t ws_size,
                              hipStream_t stream){
  const float* x  = (const float*)d_in[0];
  const float* d  = (const float*)d_in[1];
  const int*  nit = (const int*)d_in[2];
  float* out = (float*)d_out;

  // workspace carve (all fp32/int32)
  float* dn  = (float*)d_ws;                       // AA*KK
  float* fm  = dn  + (size_t)AA*KK;                // BB*AA*LPAD
  float* cmv = fm  + (size_t)BB*AA*LPAD;           // BB*AA*NC
  int*   cml = (int*)(cmv + (size_t)BB*AA*NC);     // BB*AA*NC
  float* selv = (float*)(cml + (size_t)BB*AA*NC);  // BB
  int*   sela = (int*)(selv + BB);                 // BB
  int*   selp = sela + BB;                         // BB
  size_t need = (size_t)((char*)(selp + BB) - (char*)d_ws);
  if (ws_size < need) return;  // visible failure instead of OOB corruption

  k_norm<<<AA, KK, 0, stream>>>(d, dn);
  k_zero<<<(BB*TT + 255)/256, 256, 0, stream>>>(out);
  k_fm_init<<<dim3(NC, AA/16, BB), 256, 0, stream>>>(x, dn, fm, cmv, cml);

  for (int it = 0; it < 8; ++it){
    k_argmax<<<BB, 256, 0, stream>>>(cmv, cml, selv, sela, selp, nit, it);
    k_rec<<<BB, KK, 0, stream>>>(dn, selv, sela, selp, out, nit, it);
    if (it < 7){
      k_fmupd<<<dim3(2, AA/16, BB), 256, 0, stream>>>(dn, selv, sela, selp, fm, nit, it);
      k_cmref<<<dim3(3, AA/16, BB), 256, 0, stream>>>(fm, cmv, cml, selp, nit, it);
    }
  }
}

// Round 6
// 533.414 us; speedup vs baseline: 1.5348x; 1.5348x over previous
//
#include <hip/hip_runtime.h>
#include <cstddef>
#include <cstdint>

// Problem constants (from setup_inputs)
#define AA 512      // atoms
#define KK 256      // atom size
#define TT 16384    // signal length
#define BB 4        // batch
#define PP 128      // pad = K/2
#define LL 16385    // feature map length = T + 2P - K + 1
#define LPAD 16388  // fm row stride, padded to multiple of 4 for float4 stores
#define NC 65       // number of 256-wide chunks covering LL
#define NT2 33      // position tiles of 512 covering LL
#define SDN 260     // s_dn row stride (floats): 16B-aligned, bank offset 4/row

// 4-float-granularity LDS swizzle: bank rotation of 4 per 32-float block.
// Keeps any 4-aligned float4 16B-aligned; refill lanes land 2-way max (free).
static __device__ __forceinline__ int swz4(int i){ return i + ((i >> 5) << 2); }

// ---------------- normalize dictionary atoms ----------------
__global__ void k_norm(const float* __restrict__ d, float* __restrict__ dn){
  int a = blockIdx.x, t = threadIdx.x;
  float v = d[a*KK + t];
  float s = v*v;
  #pragma unroll
  for (int off = 32; off > 0; off >>= 1) s += __shfl_down(s, off, 64);
  __shared__ float red[4];
  if ((t & 63) == 0) red[t >> 6] = s;
  __syncthreads();
  float tot = red[0] + red[1] + red[2] + red[3];
  dn[a*KK + t] = v / (sqrtf(tot) + 1e-8f);
}

// ---------------- zero output ----------------
__global__ void k_zero(float* __restrict__ out){
  int i = blockIdx.x*blockDim.x + threadIdx.x;
  if (i < BB*TT) out[i] = 0.f;
}

// ---------------- 32-position ring-buffer correlation core ----------------
// acc[j] = sum_{k=0..255} dnrow[k] * s_r[swz4(32*tx + j + k)], j = 0..31.
// K-ascending fmaf chain per acc[j] == previous corr16 order (bitwise-equal fm).
// dnrow must be 16B-aligned with k accessible at stride 1 (SDN-stride rows).
__device__ __forceinline__ void corr32(const float* __restrict__ s_r,
                                       const float* __restrict__ dnrow,
                                       int tx, float acc[32]){
  const int base = tx*32;
  float r[32];
  #pragma unroll
  for (int q = 0; q < 8; ++q){
    float4 v = *(const float4*)(s_r + swz4(base + 4*q));
    r[4*q] = v.x; r[4*q+1] = v.y; r[4*q+2] = v.z; r[4*q+3] = v.w;
  }
  #pragma unroll
  for (int j = 0; j < 32; ++j) acc[j] = 0.f;
  for (int kb = 0; kb < 8; ++kb){            // k = kb*32 + kq*4 + kk
    #pragma unroll
    for (int kq = 0; kq < 8; ++kq){
      const int k0 = kb*32 + kq*4;
      const float4 w4 = *(const float4*)(dnrow + k0);             // 4 weights
      const float4 f4 = *(const float4*)(s_r + swz4(base + k0 + 32)); // 4 refills
      #pragma unroll
      for (int kk = 0; kk < 4; ++kk){
        const float w = (&w4.x)[kk];
        const int km = (kq*4 + kk) & 31;     // k mod 32, compile-time
        #pragma unroll
        for (int j = 0; j < 32; ++j)
          acc[j] = fmaf(w, r[(km + j) & 31], acc[j]);
        r[km] = (&f4.x)[kk];                 // window slides by 1
      }
    }
  }
}

// ---------------- initial feature map + chunk maxima ----------------
// block: 256 thr = 16 tx (32 positions each) x 16 ty (atoms); tile 16x512
__global__ __launch_bounds__(256) void k_fm_init(const float* __restrict__ x,
                                                 const float* __restrict__ dn,
                                                 float* __restrict__ fm,
                                                 float* __restrict__ cmv,
                                                 int* __restrict__ cml){
  const int lt = blockIdx.x, at = blockIdx.y, b = blockIdx.z;
  const int l0 = lt*512, a0 = at*16;
  const int tid = threadIdx.x;
  const int tx = tid & 15, ty = tid >> 4;

  __shared__ __align__(16) float s_r[860];      // 768 swizzled floats
  __shared__ __align__(16) float s_dn[16*SDN];  // 16 atoms, stride 260

  for (int i = tid; i < 768; i += 256){
    int t = l0 + i - PP;                        // padded coords -> signal index
    s_r[swz4(i)] = (t >= 0 && t < TT) ? x[b*TT + t] : 0.f;
  }
  for (int i = tid; i < 16*KK; i += 256){
    int aa = i >> 8, k = i & 255;
    s_dn[aa*SDN + k] = dn[(size_t)(a0 + aa)*KK + k];
  }
  __syncthreads();

  float acc[32];
  corr32(s_r, &s_dn[ty*SDN], tx, acc);

  const int base = tx*32;
  const size_t rowoff = ((size_t)b*AA + a0 + ty)*LPAD + l0 + base;
  float best = -1e30f; int bestl = l0 + base;
  if (l0 + 512 <= LL){
    #pragma unroll
    for (int q = 0; q < 8; ++q){
      float4 v4; v4.x = acc[4*q]; v4.y = acc[4*q+1]; v4.z = acc[4*q+2]; v4.w = acc[4*q+3];
      *(float4*)(fm + rowoff + 4*q) = v4;
    }
    #pragma unroll
    for (int j = 0; j < 32; ++j)
      if (acc[j] > best){ best = acc[j]; bestl = l0 + base + j; }
  } else {
    #pragma unroll
    for (int j = 0; j < 32; ++j){
      int l = l0 + base + j;
      if (l < LL){
        fm[rowoff + j] = acc[j];
        if (acc[j] > best){ best = acc[j]; bestl = l; }
      }
    }
  }
  // thread's 32 positions sit in one 256-chunk: chunk = lt*2 + (tx>>3).
  // reduce across the 8 tx lanes of that chunk (within wave, same ty)
  #pragma unroll
  for (int m = 1; m < 8; m <<= 1){
    float ov = __shfl_xor(best, m, 64);
    int   ol = __shfl_xor(bestl, m, 64);
    if (ov > best || (ov == best && ol < bestl)){ best = ov; bestl = ol; }
  }
  int ch = lt*2 + (tx >> 3);
  if ((tx & 7) == 0 && ch < NC){
    size_t ci = ((size_t)b*AA + a0 + ty)*NC + ch;
    cmv[ci] = best; cml[ci] = bestl;
  }
}

// ---------------- per-atom row max from chunk maxima ----------------
__global__ void k_rowmax0(const float* __restrict__ cmv, const int* __restrict__ cml,
                          float* __restrict__ amv, int* __restrict__ aml){
  const int a0 = blockIdx.x*16, b = blockIdx.y;
  const int tx = threadIdx.x & 15, ty = threadIdx.x >> 4;
  const size_t row = (size_t)b*AA + a0 + ty;
  float best = -1e30f; int bestl = 0;
  for (int c = tx; c < NC; c += 16){
    float v = cmv[row*NC + c]; int l = cml[row*NC + c];
    if (v > best || (v == best && l < bestl)){ best = v; bestl = l; }
  }
  #pragma unroll
  for (int m = 1; m < 16; m <<= 1){
    float ov = __shfl_xor(best, m, 64);
    int   ol = __shfl_xor(bestl, m, 64);
    if (ov > best || (ov == best && ol < bestl)){ best = ov; bestl = ol; }
  }
  if (tx == 0){ amv[b*AA + a0 + ty] = best; aml[b*AA + a0 + ty] = bestl; }
}

// ---------------- select best atom (argmax over amv) + write reconstruction ----------------
__global__ void k_sel(const float* __restrict__ amv, const int* __restrict__ aml,
                      const float* __restrict__ dn,
                      float* __restrict__ selv, int* __restrict__ sela, int* __restrict__ selp,
                      float* __restrict__ out, const int* __restrict__ nit, int it){
  if (it >= *nit) return;
  const int b = blockIdx.x, tid = threadIdx.x;
  float best = amv[b*AA + tid]; int ba = tid, bl = aml[b*AA + tid];
  {
    float v = amv[b*AA + tid + 256]; int l = aml[b*AA + tid + 256];
    if (v > best){ best = v; ba = tid + 256; bl = l; }   // larger index only on strict >
  }
  __shared__ float sv[256]; __shared__ int sa[256]; __shared__ int sl[256];
  sv[tid] = best; sa[tid] = ba; sl[tid] = bl;
  __syncthreads();
  for (int s = 128; s > 0; s >>= 1){
    if (tid < s){
      float ov = sv[tid+s]; int oa = sa[tid+s], ol = sl[tid+s];
      bool take = ov > sv[tid] || (ov == sv[tid] && oa < sa[tid]);
      if (take){ sv[tid] = ov; sa[tid] = oa; sl[tid] = ol; }
    }
    __syncthreads();
  }
  if (tid == 0){ selv[b] = sv[0]; sela[b] = sa[0]; selp[b] = sl[0]; }
  __syncthreads();
  const float val = sv[0]; const int c = sa[0], pos = sl[0];
  int t = pos + tid - PP;
  if (t >= 0 && t < TT) out[b*TT + t] += val * dn[c*KK + tid];
}

// ---------------- fused update: fm -= val*G, refresh chunk maxima + row maxima ----------------
// grid (AA/16, BB); block 256 = 16 tx x 16 ty(atoms). G(a,c,s) over full s in [-256,256).
__global__ __launch_bounds__(256) void k_upd(const float* __restrict__ dn,
                                             const float* __restrict__ selv,
                                             const int* __restrict__ sela,
                                             const int* __restrict__ selp,
                                             float* __restrict__ fm,
                                             float* __restrict__ cmv, int* __restrict__ cml,
                                             float* __restrict__ amv, int* __restrict__ aml,
                                             const int* __restrict__ nit, int it){
  if (it >= *nit) return;
  const int a0 = blockIdx.x*16, b = blockIdx.y;
  const float val = selv[b]; const int c = sela[b], pos = selp[b];
  const int tid = threadIdx.x, tx = tid & 15, ty = tid >> 4;

  __shared__ __align__(16) float s_e[860];      // zero-extended dn[c]: e[i]=dn_c[i-256]
  __shared__ __align__(16) float s_dn[16*SDN];

  for (int i = tid; i < 768; i += 256){
    int k = i - 256;
    s_e[swz4(i)] = (k >= 0 && k < KK) ? dn[(size_t)c*KK + k] : 0.f;
  }
  for (int i = tid; i < 16*KK; i += 256){
    int aa = i >> 8, k = i & 255;
    s_dn[aa*SDN + k] = dn[(size_t)(a0 + aa)*KK + k];
  }
  __syncthreads();

  float acc[32];                                // acc[j] = G(a0+ty, c, 32*tx + j - 256)
  corr32(s_e, &s_dn[ty*SDN], tx, acc);

  const size_t rb = ((size_t)b*AA + a0 + ty)*LPAD;
  const int lb = pos - 256 + tx*32;
  #pragma unroll
  for (int j = 0; j < 32; ++j){
    int l = lb + j;
    if (l >= 0 && l < LL) fm[rb + l] -= val * acc[j];
  }
  __syncthreads();   // all fm updates by this block visible block-wide

  // refresh the touched chunks (<=3) for this block's atoms
  int lo = pos - 255; if (lo < 0) lo = 0;
  int hi = pos + 255; if (hi > LL-1) hi = LL-1;
  const int c0 = lo >> 8, c1 = hi >> 8;
  for (int ch = c0; ch <= c1; ++ch){
    int lbase = ch*256 + tx*16;
    float best = -1e30f; int bestl = lbase;
    #pragma unroll
    for (int j = 0; j < 16; ++j){
      int l = lbase + j;
      if (l < LL){
        float v = fm[rb + l];
        if (v > best){ best = v; bestl = l; }
      }
    }
    #pragma unroll
    for (int m = 1; m < 16; m <<= 1){
      float ov = __shfl_xor(best, m, 64);
      int   ol = __shfl_xor(bestl, m, 64);
      if (ov > best || (ov == best && ol < bestl)){ best = ov; bestl = ol; }
    }
    if (tx == 0){
      size_t ci = ((size_t)b*AA + a0 + ty)*NC + ch;
      cmv[ci] = best; cml[ci] = bestl;
    }
  }
  __syncthreads();   // fresh cmv/cml visible block-wide

  // recompute this block's 16 per-atom row maxima over all 65 chunks
  const size_t row = (size_t)b*AA + a0 + ty;
  float best = -1e30f; int bestl = 0;
  for (int cc = tx; cc < NC; cc += 16){
    float v = cmv[row*NC + cc]; int l = cml[row*NC + cc];
    if (v > best || (v == best && l < bestl)){ best = v; bestl = l; }
  }
  #pragma unroll
  for (int m = 1; m < 16; m <<= 1){
    float ov = __shfl_xor(best, m, 64);
    int   ol = __shfl_xor(bestl, m, 64);
    if (ov > best || (ov == best && ol < bestl)){ best = ov; bestl = ol; }
  }
  if (tx == 0){ amv[b*AA + a0 + ty] = best; aml[b*AA + a0 + ty] = bestl; }
}

extern "C" void kernel_launch(void* const* d_in, const int* in_sizes, int n_in,
                              void* d_out, int out_size, void* d_ws, size_t ws_size,
                              hipStream_t stream){
  const float* x  = (const float*)d_in[0];
  const float* d  = (const float*)d_in[1];
  const int*  nit = (const int*)d_in[2];
  float* out = (float*)d_out;

  // workspace carve (all fp32/int32)
  float* dn  = (float*)d_ws;                       // AA*KK
  float* fm  = dn  + (size_t)AA*KK;                // BB*AA*LPAD
  float* cmv = fm  + (size_t)BB*AA*LPAD;           // BB*AA*NC
  int*   cml = (int*)(cmv + (size_t)BB*AA*NC);     // BB*AA*NC
  float* amv = (float*)(cml + (size_t)BB*AA*NC);   // BB*AA
  int*   aml = (int*)(amv + (size_t)BB*AA);        // BB*AA
  float* selv = (float*)(aml + (size_t)BB*AA);     // BB
  int*   sela = (int*)(selv + BB);                 // BB
  int*   selp = sela + BB;                         // BB
  size_t need = (size_t)((char*)(selp + BB) - (char*)d_ws);
  if (ws_size < need) return;  // visible failure instead of OOB corruption

  k_norm<<<AA, KK, 0, stream>>>(d, dn);
  k_zero<<<(BB*TT + 255)/256, 256, 0, stream>>>(out);
  k_fm_init<<<dim3(NT2, AA/16, BB), 256, 0, stream>>>(x, dn, fm, cmv, cml);
  k_rowmax0<<<dim3(AA/16, BB), 256, 0, stream>>>(cmv, cml, amv, aml);

  for (int it = 0; it < 8; ++it){
    k_sel<<<BB, 256, 0, stream>>>(amv, aml, dn, selv, sela, selp, out, nit, it);
    if (it < 7){
      k_upd<<<dim3(AA/16, BB), 256, 0, stream>>>(dn, selv, sela, selp, fm,
                                                 cmv, cml, amv, aml, nit, it);
    }
  }
}